// Round 3
// baseline (388.391 us; speedup 1.0000x reference)
//
#include <hip/hip_runtime.h>
#include <hip/hip_fp16.h>
#include <cmath>

// RestorationLoss = (1 - mean(SSIM(r_low, r_high))) + mean((r_low - r_high)^2)
// Separable 11x11 gaussian; 4 conv fields: mu1, mu2, S=conv(a^2+b^2), P=conv(ab).
// out = 1 + sum(d^2 - ssim_px)/N.
// R14 = R13 skeleton + fp16-packed LDS staging (occupancy round).
// R13 post-mortem: dur pinned ~86us across 3 configs while VALUBusy fell
// 71->52% -- latency-bound; LDS blocks/CU (3-4) caps waves at 12-16/CU.
//  - hbuf: float4 -> uint2 (2x half2: (mu1,mu2),(S,P)), 39.1 -> 19.5 KB
//    -> 8 blocks/CU * 4 waves = 32 waves/CU (full slots).
//  - launch_bounds(256,8): forces VGPR<=64 (R13 used 60; required for 8 w/SIMD
//    per m69 quantization). Watch for scratch if allocator overflows.
//  - precision: fields in [0,2), fp16 err ~5e-4/field; biases cancel in
//    S-mu^2 and P-mu1mu2; final mean bias ~1e-4 << 2.3e-2 threshold.
//  - VALU +7%: 8 cvt_pkrtz/convStore, 4 cvt_f32_f16 per j in phase 2.
// Frozen: 32x64 tile, interleaved padded hbuf[74][33], rcp ssim epilogue,
// float4-aligned conditional edge loads, 256 thr, R9 load/conv pipeline.

#define HH 512
#define WW 512
#define TILE_H 64
#define TILE_W 32
#define HB (TILE_H + 10)                          // 74 staged rows
#define LDW 33                                    // padded row: 33 uint2
#define NPLANES 48
#define CT (WW / TILE_W)                          // 16
#define RT (HH / TILE_H)                          // 8
#define NBLOCKS (NPLANES * RT * CT)               // 6144

struct GW { float g[11]; };

__device__ __forceinline__ unsigned pack2(float a, float b) {
    __half2 h = __floats2half2_rn(a, b);
    return __builtin_bit_cast(unsigned, h);
}
__device__ __forceinline__ float2 unpack2(unsigned u) {
    __half2 h = __builtin_bit_cast(__half2, u);
    return __half22float2(h);
}

__global__ __launch_bounds__(256, 8)
void ssim_main(const float* __restrict__ img1, const float* __restrict__ img2,
               float* __restrict__ partial, GW gw)
{
    __shared__ uint2 hbuf[HB][LDW];               // (mu1,mu2)|(S,P) fp16: 19536 B
    __shared__ float red[4];

    const int tid   = threadIdx.x;
    const int bx    = blockIdx.x;
    const int by    = blockIdx.y;
    const int plane = blockIdx.z;
    const int row0  = by * TILE_H;
    const int col0  = bx * TILE_W;
    const float* p1 = img1 + (size_t)plane * (HH * WW);
    const float* p2 = img2 + (size_t)plane * (HH * WW);

    const int cg    = tid & 7;                    // col group: tile cols 4cg..4cg+3
    const int rs    = tid >> 3;                   // 0..31 row slot
    const int cbase = col0 + 4 * cg - 8;          // 20-float window, 16B aligned

    // 5 conditional float4 loads; OOB vectors (col OR row) become zeros.
    // Valid: all OOB col spans are float4-aligned since cbase%4==0 and the
    // 0/512 limits are too. Row-OOB zero-fill == reference zero padding.
    auto loadRow = [&](int grow, float4* x1, float4* x2) {
        const bool rowOK = (grow >= 0 && grow < HH);
        const int growc = min(max(grow, 0), HH - 1);      // addr always in-bounds
        const float* r1 = p1 + (size_t)growc * WW;
        const float* r2 = p2 + (size_t)growc * WW;
        #pragma unroll
        for (int v = 0; v < 5; ++v) {
            const int c0 = cbase + 4 * v;
            if (rowOK && c0 >= 0 && c0 + 4 <= WW) {
                x1[v] = *reinterpret_cast<const float4*>(r1 + c0);
                x2[v] = *reinterpret_cast<const float4*>(r2 + c0);
            } else {
                x1[v] = make_float4(0.f, 0.f, 0.f, 0.f);
                x2[v] = make_float4(0.f, 0.f, 0.f, 0.f);
            }
        }
    };

    // horizontal conv of one staged row -> packed fp16 hbuf[rl][col]
    auto convStore = [&](int rl, const float4* x1v, const float4* x2v) {
        const float* x1 = reinterpret_cast<const float*>(x1v);
        const float* x2 = reinterpret_cast<const float*>(x2v);
        float acc[4][4];
        #pragma unroll
        for (int k = 0; k < 4; ++k)
            #pragma unroll
            for (int i = 0; i < 4; ++i) acc[k][i] = 0.f;
        #pragma unroll
        for (int e = 3; e <= 16; ++e) {           // out col i uses e = i+j+3
            float a  = x1[e], b = x2[e];
            float v2 = a * a + b * b;
            float v3 = a * b;
            #pragma unroll
            for (int i = 0; i < 4; ++i) {
                int j = e - 3 - i;
                if (j >= 0 && j < 11) {
                    float w = gw.g[j];
                    acc[0][i] += w * a;
                    acc[1][i] += w * b;
                    acc[2][i] += w * v2;
                    acc[3][i] += w * v3;
                }
            }
        }
        #pragma unroll
        for (int i = 0; i < 4; ++i) {
            uint2 px;
            px.x = pack2(acc[0][i], acc[1][i]);
            px.y = pack2(acc[2][i], acc[3][i]);
            hbuf[rl][4 * cg + i] = px;            // 4 adjacent b64 (merge to b128)
        }
    };

    // ---- Phase 1: software-pipelined; 74 rows = 32 + 32 + 10 ----
    {
        float4 xA1[5], xA2[5], xB1[5], xB2[5];
        const bool third = (rs < 10);
        loadRow(row0 - 5 + rs, xA1, xA2);         // rows 0..31
        loadRow(row0 + 27 + rs, xB1, xB2);        // rows 32..63
        convStore(rs, xA1, xA2);                  // under B's load latency
        if (third) loadRow(row0 + 59 + rs, xA1, xA2);  // rows 64..73 (reuse A regs)
        convStore(rs + 32, xB1, xB2);             // under C's load latency
        if (third) convStore(rs + 64, xA1, xA2);
    }

    // ---- MSE pixel prefetch, vectorized (no LDS dep; consumed after barrier)
    const int mc = (tid & 7) * 4;                 // float4 col
    const int mr = tid >> 3;                      // 0..31 -> rows 2mr, 2mr+1
    float4 mse_a[2], mse_b[2];
    #pragma unroll
    for (int q = 0; q < 2; ++q) {
        size_t off = (size_t)(row0 + 2 * mr + q) * WW + col0 + mc;
        mse_a[q] = *reinterpret_cast<const float4*>(p1 + off);
        mse_b[q] = *reinterpret_cast<const float4*>(p2 + off);
    }
    __syncthreads();

    // ---- Phase 2: vertical conv (18 b64 reads / 8 rows) + ssim + mse ----
    float local = 0.f;
    {
        const int tx = tid & 31;                  // pixel column
        const int rg = tid >> 5;                  // 0..7 -> rows 8rg..8rg+7
        float4 res[8];
        #pragma unroll
        for (int p = 0; p < 8; ++p) res[p] = make_float4(0.f, 0.f, 0.f, 0.f);
        #pragma unroll
        for (int j = 0; j < 18; ++j) {            // window rows rg*8 .. rg*8+17
            uint2 u = hbuf[rg * 8 + j][tx];
            float2 f01 = unpack2(u.x);            // mu1, mu2
            float2 f23 = unpack2(u.y);            // S, P
            #pragma unroll
            for (int p = 0; p < 8; ++p) {
                int t = j - p;
                if (t >= 0 && t < 11) {
                    float w = gw.g[t];
                    res[p].x += w * f01.x;
                    res[p].y += w * f01.y;
                    res[p].z += w * f23.x;
                    res[p].w += w * f23.y;
                }
            }
        }
        const float C1c = 0.0001f, C2c = 0.0009f;
        #pragma unroll
        for (int p = 0; p < 8; ++p) {
            float mu1 = res[p].x, mu2 = res[p].y;
            float S   = res[p].z, P   = res[p].w;
            float m11 = mu1 * mu1, m22 = mu2 * mu2, m12 = mu1 * mu2;
            float num = (2.f * m12 + C1c) * (2.f * (P - m12) + C2c);
            float den = (m11 + m22 + C1c) * ((S - m11 - m22) + C2c);
            float inv = __builtin_amdgcn_rcpf(den);   // ~1ulp, fine vs 2.3e-2
            local -= num * inv;
        }
        // MSE on this thread's (different) 8 px — global sum, mapping-free
        #pragma unroll
        for (int q = 0; q < 2; ++q) {
            float dx = mse_a[q].x - mse_b[q].x;
            float dy = mse_a[q].y - mse_b[q].y;
            float dz = mse_a[q].z - mse_b[q].z;
            float dw = mse_a[q].w - mse_b[q].w;
            local += dx * dx + dy * dy + dz * dz + dw * dw;
        }
    }

    // ---- block reduce ----
    #pragma unroll
    for (int off = 32; off > 0; off >>= 1) local += __shfl_down(local, off);
    if ((tid & 63) == 0) red[tid >> 6] = local;
    __syncthreads();
    if (tid == 0) {
        int bid = (plane * RT + by) * CT + bx;
        partial[bid] = (red[0] + red[1]) + (red[2] + red[3]);
    }
}

__global__ __launch_bounds__(256)
void ssim_finish(const float* __restrict__ partial, float* __restrict__ out)
{
    __shared__ float red[256];
    float s = 0.f;
    #pragma unroll
    for (int i = 0; i < NBLOCKS / 256; ++i)       // 24 independent loads
        s += partial[i * 256 + threadIdx.x];
    red[threadIdx.x] = s;
    __syncthreads();
    for (int step = 128; step > 0; step >>= 1) {
        if ((int)threadIdx.x < step) red[threadIdx.x] += red[threadIdx.x + step];
        __syncthreads();
    }
    if (threadIdx.x == 0)
        out[0] = 1.0f + red[0] * (1.0f / 12582912.0f);
}

extern "C" void kernel_launch(void* const* d_in, const int* in_sizes, int n_in,
                              void* d_out, int out_size, void* d_ws, size_t ws_size,
                              hipStream_t stream)
{
    const float* r_low  = (const float*)d_in[0];
    const float* r_high = (const float*)d_in[1];
    float* out     = (float*)d_out;
    float* partial = (float*)d_ws;                       // 6144 floats = 24 KB

    GW gw;                                               // gaussian -> SGPRs
    {
        float s = 0.f;
        for (int i = 0; i < 11; ++i) {
            float c = (float)(i - 5);
            gw.g[i] = expf(-(c * c) / 4.5f);             // 2*sigma^2 = 4.5
            s += gw.g[i];
        }
        for (int i = 0; i < 11; ++i) gw.g[i] /= s;
    }

    dim3 grid(CT, RT, NPLANES);
    ssim_main<<<grid, dim3(256), 0, stream>>>(r_low, r_high, partial, gw);
    ssim_finish<<<1, dim3(256), 0, stream>>>(partial, out);
}

// Round 4
// 164.256 us; speedup vs baseline: 2.3646x; 2.3646x over previous
//
#include <hip/hip_runtime.h>
#include <hip/hip_fp16.h>
#include <cmath>

// RestorationLoss = (1 - mean(SSIM(r_low, r_high))) + mean((r_low - r_high)^2)
// Separable 11x11 gaussian; 4 conv fields: mu1, mu2, S=conv(a^2+b^2), P=conv(ab).
// out = 1 + sum(d^2 - ssim_px)/N.
// R15 = R13 skeleton + fp16 LDS staging, WITHOUT the R14 register cap.
// R14 post-mortem: launch_bounds(256,8) forced VGPR=32 << phase-1 live set
// (~80) -> 678 MB scratch spill, 313us. Fix occupancy by REMOVING pressure:
//  - MSE folded into phase-1 convStore: x1[8..11] are exactly the thread's
//    4 tile columns (always in-bounds), staged rows rl in [5,68] are exactly
//    the 64 tile rows, each tile pixel hit once. Kills the 16-VGPR mse
//    prefetch that was live across phase 2 + 8 global loads/thread.
//  - hbuf float4 -> uint2 (2x half2): 39.1 -> 19.5 KB. Fields in [0,2),
//    fp16 err ~5e-4, biases cancel in S-mu^2 / P-mu1mu2; mean bias ~1e-4
//    << 2.3e-2 threshold.
//  - launch_bounds(256,4): cap 128 (no spill); actual VGPR ~56-62 (<=64
//    breakpoint, m69) -> HW can run 8 blocks/CU (LDS 19968 allows 8).
// Frozen: 32x64 tile, padded hbuf[74][33], rcp ssim epilogue, float4-aligned
// conditional edge loads, 256 thr, R9 load/conv pipeline.

#define HH 512
#define WW 512
#define TILE_H 64
#define TILE_W 32
#define HB (TILE_H + 10)                          // 74 staged rows
#define LDW 33                                    // padded row: 33 uint2
#define NPLANES 48
#define CT (WW / TILE_W)                          // 16
#define RT (HH / TILE_H)                          // 8
#define NBLOCKS (NPLANES * RT * CT)               // 6144

struct GW { float g[11]; };

__device__ __forceinline__ unsigned pack2(float a, float b) {
    __half2 h = __floats2half2_rn(a, b);
    return __builtin_bit_cast(unsigned, h);
}
__device__ __forceinline__ float2 unpack2(unsigned u) {
    __half2 h = __builtin_bit_cast(__half2, u);
    return __half22float2(h);
}

__global__ __launch_bounds__(256, 4)
void ssim_main(const float* __restrict__ img1, const float* __restrict__ img2,
               float* __restrict__ partial, GW gw)
{
    __shared__ uint2 hbuf[HB][LDW];               // (mu1,mu2)|(S,P) fp16: 19536 B
    __shared__ float red[4];

    const int tid   = threadIdx.x;
    const int bx    = blockIdx.x;
    const int by    = blockIdx.y;
    const int plane = blockIdx.z;
    const int row0  = by * TILE_H;
    const int col0  = bx * TILE_W;
    const float* p1 = img1 + (size_t)plane * (HH * WW);
    const float* p2 = img2 + (size_t)plane * (HH * WW);

    const int cg    = tid & 7;                    // col group: tile cols 4cg..4cg+3
    const int rs    = tid >> 3;                   // 0..31 row slot
    const int cbase = col0 + 4 * cg - 8;          // 20-float window, 16B aligned

    float local = 0.f;                            // mse (phase 1) - ssim (phase 2)

    // 5 conditional float4 loads; OOB vectors (col OR row) become zeros.
    // Valid: all OOB col spans are float4-aligned since cbase%4==0 and the
    // 0/512 limits are too. Row-OOB zero-fill == reference zero padding.
    auto loadRow = [&](int grow, float4* x1, float4* x2) {
        const bool rowOK = (grow >= 0 && grow < HH);
        const int growc = min(max(grow, 0), HH - 1);      // addr always in-bounds
        const float* r1 = p1 + (size_t)growc * WW;
        const float* r2 = p2 + (size_t)growc * WW;
        #pragma unroll
        for (int v = 0; v < 5; ++v) {
            const int c0 = cbase + 4 * v;
            if (rowOK && c0 >= 0 && c0 + 4 <= WW) {
                x1[v] = *reinterpret_cast<const float4*>(r1 + c0);
                x2[v] = *reinterpret_cast<const float4*>(r2 + c0);
            } else {
                x1[v] = make_float4(0.f, 0.f, 0.f, 0.f);
                x2[v] = make_float4(0.f, 0.f, 0.f, 0.f);
            }
        }
    };

    // horizontal conv of one staged row -> packed fp16 hbuf[rl][col]
    // + MSE for tile rows (rl in [5,68] <=> grow in [row0, row0+63])
    auto convStore = [&](int rl, const float4* x1v, const float4* x2v) {
        const float* x1 = reinterpret_cast<const float*>(x1v);
        const float* x2 = reinterpret_cast<const float*>(x2v);
        if (rl >= 5 && rl < 69) {                 // this thread's 4 tile pixels
            #pragma unroll
            for (int i = 0; i < 4; ++i) {
                float d = x1[8 + i] - x2[8 + i];
                local += d * d;
            }
        }
        float acc[4][4];
        #pragma unroll
        for (int k = 0; k < 4; ++k)
            #pragma unroll
            for (int i = 0; i < 4; ++i) acc[k][i] = 0.f;
        #pragma unroll
        for (int e = 3; e <= 16; ++e) {           // out col i uses e = i+j+3
            float a  = x1[e], b = x2[e];
            float v2 = a * a + b * b;
            float v3 = a * b;
            #pragma unroll
            for (int i = 0; i < 4; ++i) {
                int j = e - 3 - i;
                if (j >= 0 && j < 11) {
                    float w = gw.g[j];
                    acc[0][i] += w * a;
                    acc[1][i] += w * b;
                    acc[2][i] += w * v2;
                    acc[3][i] += w * v3;
                }
            }
        }
        #pragma unroll
        for (int i = 0; i < 4; ++i) {
            uint2 px;
            px.x = pack2(acc[0][i], acc[1][i]);
            px.y = pack2(acc[2][i], acc[3][i]);
            hbuf[rl][4 * cg + i] = px;            // 4 adjacent b64 (merge to b128)
        }
    };

    // ---- Phase 1: software-pipelined; 74 rows = 32 + 32 + 10 ----
    {
        float4 xA1[5], xA2[5], xB1[5], xB2[5];
        const bool third = (rs < 10);
        loadRow(row0 - 5 + rs, xA1, xA2);         // rows 0..31
        loadRow(row0 + 27 + rs, xB1, xB2);        // rows 32..63
        convStore(rs, xA1, xA2);                  // under B's load latency
        if (third) loadRow(row0 + 59 + rs, xA1, xA2);  // rows 64..73 (reuse A regs)
        convStore(rs + 32, xB1, xB2);             // under C's load latency
        if (third) convStore(rs + 64, xA1, xA2);
    }
    __syncthreads();

    // ---- Phase 2: vertical conv (18 b64 reads / 8 rows) + ssim ----
    {
        const int tx = tid & 31;                  // pixel column
        const int rg = tid >> 5;                  // 0..7 -> rows 8rg..8rg+7
        float4 res[8];
        #pragma unroll
        for (int p = 0; p < 8; ++p) res[p] = make_float4(0.f, 0.f, 0.f, 0.f);
        #pragma unroll
        for (int j = 0; j < 18; ++j) {            // window rows rg*8 .. rg*8+17
            uint2 u = hbuf[rg * 8 + j][tx];
            float2 f01 = unpack2(u.x);            // mu1, mu2
            float2 f23 = unpack2(u.y);            // S, P
            #pragma unroll
            for (int p = 0; p < 8; ++p) {
                int t = j - p;
                if (t >= 0 && t < 11) {
                    float w = gw.g[t];
                    res[p].x += w * f01.x;
                    res[p].y += w * f01.y;
                    res[p].z += w * f23.x;
                    res[p].w += w * f23.y;
                }
            }
        }
        const float C1c = 0.0001f, C2c = 0.0009f;
        #pragma unroll
        for (int p = 0; p < 8; ++p) {
            float mu1 = res[p].x, mu2 = res[p].y;
            float S   = res[p].z, P   = res[p].w;
            float m11 = mu1 * mu1, m22 = mu2 * mu2, m12 = mu1 * mu2;
            float num = (2.f * m12 + C1c) * (2.f * (P - m12) + C2c);
            float den = (m11 + m22 + C1c) * ((S - m11 - m22) + C2c);
            float inv = __builtin_amdgcn_rcpf(den);   // ~1ulp, fine vs 2.3e-2
            local -= num * inv;
        }
    }

    // ---- block reduce ----
    #pragma unroll
    for (int off = 32; off > 0; off >>= 1) local += __shfl_down(local, off);
    if ((tid & 63) == 0) red[tid >> 6] = local;
    __syncthreads();
    if (tid == 0) {
        int bid = (plane * RT + by) * CT + bx;
        partial[bid] = (red[0] + red[1]) + (red[2] + red[3]);
    }
}

__global__ __launch_bounds__(256)
void ssim_finish(const float* __restrict__ partial, float* __restrict__ out)
{
    __shared__ float red[256];
    float s = 0.f;
    #pragma unroll
    for (int i = 0; i < NBLOCKS / 256; ++i)       // 24 independent loads
        s += partial[i * 256 + threadIdx.x];
    red[threadIdx.x] = s;
    __syncthreads();
    for (int step = 128; step > 0; step >>= 1) {
        if ((int)threadIdx.x < step) red[threadIdx.x] += red[threadIdx.x + step];
        __syncthreads();
    }
    if (threadIdx.x == 0)
        out[0] = 1.0f + red[0] * (1.0f / 12582912.0f);
}

extern "C" void kernel_launch(void* const* d_in, const int* in_sizes, int n_in,
                              void* d_out, int out_size, void* d_ws, size_t ws_size,
                              hipStream_t stream)
{
    const float* r_low  = (const float*)d_in[0];
    const float* r_high = (const float*)d_in[1];
    float* out     = (float*)d_out;
    float* partial = (float*)d_ws;                       // 6144 floats = 24 KB

    GW gw;                                               // gaussian -> SGPRs
    {
        float s = 0.f;
        for (int i = 0; i < 11; ++i) {
            float c = (float)(i - 5);
            gw.g[i] = expf(-(c * c) / 4.5f);             // 2*sigma^2 = 4.5
            s += gw.g[i];
        }
        for (int i = 0; i < 11; ++i) gw.g[i] /= s;
    }

    dim3 grid(CT, RT, NPLANES);
    ssim_main<<<grid, dim3(256), 0, stream>>>(r_low, r_high, partial, gw);
    ssim_finish<<<1, dim3(256), 0, stream>>>(partial, out);
}

// Round 5
// 148.145 us; speedup vs baseline: 2.6217x; 1.1087x over previous
//
#include <hip/hip_runtime.h>
#include <hip/hip_fp16.h>
#include <cmath>

// RestorationLoss = (1 - mean(SSIM(r_low, r_high))) + mean((r_low - r_high)^2)
// Separable 11x11 gaussian; 4 conv fields: mu1, mu2, S=conv(a^2+b^2), P=conv(ab).
// out = 1 + sum(d^2 - ssim_px)/N.
// R16 = R15 + packed-fp32 conv math (issue-bound round).
// R15 post-mortem: occupancy pinned ~37% across 6/4/8-block-cap configs ->
// residency not LDS/VGPR-limited; dur = 44us VALU issue + 36us stalls.
// Attack issue count: fields pair naturally as (mu1,mu2)<-(a,b) and
// (S,P)<-(a^2+b^2, ab). ext_vector float2 accumulators let ISel emit
// v_pk_fma_f32 (VOP3P, gfx90a+/gfx950); worst case identical scalar ops.
//  - horizontal: 176 FMA -> 88 pk_fma per convStore (~-35% w/ aux)
//  - vertical:   352 FMA -> 176 pk_fma per thread  (~-45%)
// Frozen: 32x64 tile, fp16-packed hbuf[74][33] uint2 (19.5 KB), MSE folded
// into phase-1, rcp ssim epilogue, float4-aligned conditional edge loads,
// 256 thr, launch_bounds(256,4), R9 load/conv pipeline.

#define HH 512
#define WW 512
#define TILE_H 64
#define TILE_W 32
#define HB (TILE_H + 10)                          // 74 staged rows
#define LDW 33                                    // padded row: 33 uint2
#define NPLANES 48
#define CT (WW / TILE_W)                          // 16
#define RT (HH / TILE_H)                          // 8
#define NBLOCKS (NPLANES * RT * CT)               // 6144

struct GW { float g[11]; };

typedef float v2f __attribute__((ext_vector_type(2)));

__device__ __forceinline__ unsigned pack2(float a, float b) {
    __half2 h = __floats2half2_rn(a, b);
    return __builtin_bit_cast(unsigned, h);
}
__device__ __forceinline__ v2f unpack2(unsigned u) {
    __half2 h = __builtin_bit_cast(__half2, u);
    float2 f = __half22float2(h);
    return (v2f){f.x, f.y};
}

__global__ __launch_bounds__(256, 4)
void ssim_main(const float* __restrict__ img1, const float* __restrict__ img2,
               float* __restrict__ partial, GW gw)
{
    __shared__ uint2 hbuf[HB][LDW];               // (mu1,mu2)|(S,P) fp16: 19536 B
    __shared__ float red[4];

    const int tid   = threadIdx.x;
    const int bx    = blockIdx.x;
    const int by    = blockIdx.y;
    const int plane = blockIdx.z;
    const int row0  = by * TILE_H;
    const int col0  = bx * TILE_W;
    const float* p1 = img1 + (size_t)plane * (HH * WW);
    const float* p2 = img2 + (size_t)plane * (HH * WW);

    const int cg    = tid & 7;                    // col group: tile cols 4cg..4cg+3
    const int rs    = tid >> 3;                   // 0..31 row slot
    const int cbase = col0 + 4 * cg - 8;          // 20-float window, 16B aligned

    float local = 0.f;                            // mse (phase 1) - ssim (phase 2)

    // 5 conditional float4 loads; OOB vectors (col OR row) become zeros.
    // Valid: all OOB col spans are float4-aligned since cbase%4==0 and the
    // 0/512 limits are too. Row-OOB zero-fill == reference zero padding.
    auto loadRow = [&](int grow, float4* x1, float4* x2) {
        const bool rowOK = (grow >= 0 && grow < HH);
        const int growc = min(max(grow, 0), HH - 1);      // addr always in-bounds
        const float* r1 = p1 + (size_t)growc * WW;
        const float* r2 = p2 + (size_t)growc * WW;
        #pragma unroll
        for (int v = 0; v < 5; ++v) {
            const int c0 = cbase + 4 * v;
            if (rowOK && c0 >= 0 && c0 + 4 <= WW) {
                x1[v] = *reinterpret_cast<const float4*>(r1 + c0);
                x2[v] = *reinterpret_cast<const float4*>(r2 + c0);
            } else {
                x1[v] = make_float4(0.f, 0.f, 0.f, 0.f);
                x2[v] = make_float4(0.f, 0.f, 0.f, 0.f);
            }
        }
    };

    // horizontal conv of one staged row -> packed fp16 hbuf[rl][col]
    // + MSE for tile rows (rl in [5,68] <=> grow in [row0, row0+63]).
    // Packed accumulators: acc01 = (mu1,mu2), acc23 = (S,P) -> v_pk_fma_f32.
    auto convStore = [&](int rl, const float4* x1v, const float4* x2v) {
        const float* x1 = reinterpret_cast<const float*>(x1v);
        const float* x2 = reinterpret_cast<const float*>(x2v);
        if (rl >= 5 && rl < 69) {                 // this thread's 4 tile pixels
            #pragma unroll
            for (int i = 0; i < 4; ++i) {
                float d = x1[8 + i] - x2[8 + i];
                local += d * d;
            }
        }
        v2f acc01[4], acc23[4];
        #pragma unroll
        for (int i = 0; i < 4; ++i) {
            acc01[i] = (v2f){0.f, 0.f};
            acc23[i] = (v2f){0.f, 0.f};
        }
        #pragma unroll
        for (int e = 3; e <= 16; ++e) {           // out col i uses e = i+j+3
            float a  = x1[e], b = x2[e];
            v2f ab = (v2f){a, b};
            v2f t  = ab * ab;                     // pk_mul: (a^2, b^2)
            v2f vv = (v2f){t.x + t.y, a * b};     // (S-term, P-term)
            #pragma unroll
            for (int i = 0; i < 4; ++i) {
                int j = e - 3 - i;
                if (j >= 0 && j < 11) {
                    float w = gw.g[j];
                    v2f wv = (v2f){w, w};
                    acc01[i] += wv * ab;          // pk_fma
                    acc23[i] += wv * vv;          // pk_fma
                }
            }
        }
        #pragma unroll
        for (int i = 0; i < 4; ++i) {
            uint2 px;
            px.x = pack2(acc01[i].x, acc01[i].y);
            px.y = pack2(acc23[i].x, acc23[i].y);
            hbuf[rl][4 * cg + i] = px;            // 4 adjacent b64 (merge to b128)
        }
    };

    // ---- Phase 1: software-pipelined; 74 rows = 32 + 32 + 10 ----
    {
        float4 xA1[5], xA2[5], xB1[5], xB2[5];
        const bool third = (rs < 10);
        loadRow(row0 - 5 + rs, xA1, xA2);         // rows 0..31
        loadRow(row0 + 27 + rs, xB1, xB2);        // rows 32..63
        convStore(rs, xA1, xA2);                  // under B's load latency
        if (third) loadRow(row0 + 59 + rs, xA1, xA2);  // rows 64..73 (reuse A regs)
        convStore(rs + 32, xB1, xB2);             // under C's load latency
        if (third) convStore(rs + 64, xA1, xA2);
    }
    __syncthreads();

    // ---- Phase 2: vertical conv (18 b64 reads / 8 rows) + ssim ----
    {
        const int tx = tid & 31;                  // pixel column
        const int rg = tid >> 5;                  // 0..7 -> rows 8rg..8rg+7
        v2f res01[8], res23[8];
        #pragma unroll
        for (int p = 0; p < 8; ++p) {
            res01[p] = (v2f){0.f, 0.f};
            res23[p] = (v2f){0.f, 0.f};
        }
        #pragma unroll
        for (int j = 0; j < 18; ++j) {            // window rows rg*8 .. rg*8+17
            uint2 u = hbuf[rg * 8 + j][tx];
            v2f f01 = unpack2(u.x);               // (mu1, mu2)
            v2f f23 = unpack2(u.y);               // (S, P)
            #pragma unroll
            for (int p = 0; p < 8; ++p) {
                int t = j - p;
                if (t >= 0 && t < 11) {
                    float w = gw.g[t];
                    v2f wv = (v2f){w, w};
                    res01[p] += wv * f01;         // pk_fma
                    res23[p] += wv * f23;         // pk_fma
                }
            }
        }
        const float C1c = 0.0001f, C2c = 0.0009f;
        #pragma unroll
        for (int p = 0; p < 8; ++p) {
            float mu1 = res01[p].x, mu2 = res01[p].y;
            float S   = res23[p].x, P   = res23[p].y;
            float m11 = mu1 * mu1, m22 = mu2 * mu2, m12 = mu1 * mu2;
            float num = (2.f * m12 + C1c) * (2.f * (P - m12) + C2c);
            float den = (m11 + m22 + C1c) * ((S - m11 - m22) + C2c);
            float inv = __builtin_amdgcn_rcpf(den);   // ~1ulp, fine vs 2.3e-2
            local -= num * inv;
        }
    }

    // ---- block reduce ----
    #pragma unroll
    for (int off = 32; off > 0; off >>= 1) local += __shfl_down(local, off);
    if ((tid & 63) == 0) red[tid >> 6] = local;
    __syncthreads();
    if (tid == 0) {
        int bid = (plane * RT + by) * CT + bx;
        partial[bid] = (red[0] + red[1]) + (red[2] + red[3]);
    }
}

__global__ __launch_bounds__(256)
void ssim_finish(const float* __restrict__ partial, float* __restrict__ out)
{
    __shared__ float red[256];
    float s = 0.f;
    #pragma unroll
    for (int i = 0; i < NBLOCKS / 256; ++i)       // 24 independent loads
        s += partial[i * 256 + threadIdx.x];
    red[threadIdx.x] = s;
    __syncthreads();
    for (int step = 128; step > 0; step >>= 1) {
        if ((int)threadIdx.x < step) red[threadIdx.x] += red[threadIdx.x + step];
        __syncthreads();
    }
    if (threadIdx.x == 0)
        out[0] = 1.0f + red[0] * (1.0f / 12582912.0f);
}

extern "C" void kernel_launch(void* const* d_in, const int* in_sizes, int n_in,
                              void* d_out, int out_size, void* d_ws, size_t ws_size,
                              hipStream_t stream)
{
    const float* r_low  = (const float*)d_in[0];
    const float* r_high = (const float*)d_in[1];
    float* out     = (float*)d_out;
    float* partial = (float*)d_ws;                       // 6144 floats = 24 KB

    GW gw;                                               // gaussian -> SGPRs
    {
        float s = 0.f;
        for (int i = 0; i < 11; ++i) {
            float c = (float)(i - 5);
            gw.g[i] = expf(-(c * c) / 4.5f);             // 2*sigma^2 = 4.5
            s += gw.g[i];
        }
        for (int i = 0; i < 11; ++i) gw.g[i] /= s;
    }

    dim3 grid(CT, RT, NPLANES);
    ssim_main<<<grid, dim3(256), 0, stream>>>(r_low, r_high, partial, gw);
    ssim_finish<<<1, dim3(256), 0, stream>>>(partial, out);
}